// Round 5
// baseline (850.636 us; speedup 1.0000x reference)
//
#include <hip/hip_runtime.h>

// Fused SpikingDenseLayer: B=256, T=100, F=K=1024, U=1024.
// One block = one (batch b, 128-wide u-tile), 256 threads.
// v6 = v5 with the LDS-read-pipe bottleneck removed:
//  * v5 model: per kk-iter 4 ds_read_b128 + 7 ds_read_b64 ~= 90 LDS-pipe
//    cyc/wave vs 224 VALU cyc; LDS pipe is per-CU -> 614 us LDS-bound
//    (measured 630). Fix: B (W) is read DIRECT FROM GLOBAL (L1/L2-hot,
//    8 KB k-slice shared by all 256 batch blocks; SGPR base + 4*ug lane
//    offset, 4 cache lines/request). LDS drops to 42 cyc/iter (287 us)
//    < 382 us FMA floor.
//  * As staging double-buffered (2 x 6.4 KB; fits under Cs 26.4 KB):
//    stage tile t+1 issued BEFORE compute of tile t, ONE barrier/tile;
//    the auto vmcnt(0)@barrier drains after ~1792 cyc of FMA cover.
//    Static ping-pong (two COMPUTE calls) -- no runtime buffer index.
//  * kk loop stays rolled (#pragma unroll 1): v4 showed full unroll makes
//    hipcc hoist all loads -> spill. No __launch_bounds__ min-waves arg
//    (measured cap ~= 256/arg would re-spill).
//  * tail rows t=96..99 wave-uniform on wave 0; 100 issued rows exactly.
// Per-output FMA chain strictly k-ascending, same expression forms as the
// passing v5 -> currents bitwise identical; scan math unchanged.

#define UN 128              // u-columns per block
#define BK 16               // k-slice staged per buffer
#define CS 132              // Cs row stride in floats (128 + 4)
#define CHUNK 50            // t-rows per scan chunk
#define TMAX 100

__device__ __forceinline__ void gload_lds16(const float* g, float* l) {
    __builtin_amdgcn_global_load_lds(
        (const __attribute__((address_space(1))) void*)g,
        (__attribute__((address_space(3))) void*)l,
        16, 0, 0);
}

__global__ __launch_bounds__(256) void fused_snn(
    const float* __restrict__ x,     // [B,T,F]
    const float* __restrict__ W,     // [F,U]
    const float* __restrict__ bias,  // [U]
    float* __restrict__ spikes,      // [B,T,U]
    float* __restrict__ counts,      // [B,U]
    int B, int T, int F, int U)
{
    // smem: As double-buffer (2 x 1600 floats) during GEMM; whole region
    // reused as Cs[50][132] for the scan.
    __shared__ __align__(16) float smem[CHUNK * CS];   // 6600 floats = 26.4 KB
    float* As0 = smem;           // [100][16] linear
    float* As1 = smem + 1600;    // [100][16] linear

    const int tid = threadIdx.x;
    const int tg  = tid >> 4;    // 0..15 -> t = i*16 + tg
    const int ug  = tid & 15;    // 0..15 -> u cols {4ug..} and {64+4ug..}
    const int u0  = blockIdx.x * UN;
    const int b   = blockIdx.y;

    float acc[7][8];
    #pragma unroll
    for (int i = 0; i < 7; i++)
        #pragma unroll
        for (int j = 0; j < 8; j++) acc[i][j] = 0.f;

    const float* xb = x + (size_t)b * T * F;

    // A staging: 100 rows x 64 B = 400 16-B slots; slot s = row s>>2,
    // byte (s&3)*16; LDS dest = slot*16 (linear, as global_load_lds needs).
    const float* ga0 = xb + (size_t)(tid >> 2) * F + (tid & 3) * 4;
    const float* ga1 = xb + (size_t)(64 + (tid >> 2)) * F + (tid & 3) * 4;
    const int la0 = tid * 4;
    const int la1 = (256 + tid) * 4;
    const bool a1on = (tid < 144);           // slots 256..399
    const bool w0   = (tid < 64);            // wave 0 owns tail rows 96..99

#define STAGE(buf, kof)                                   \
    do {                                                  \
        gload_lds16(ga0 + (kof), (buf) + la0);            \
        if (a1on) gload_lds16(ga1 + (kof), (buf) + la1);  \
    } while (0)

#define COMPUTE(buf, k0b)                                                  \
    do {                                                                   \
        const float* ap = (buf) + tg * 16;                                 \
        _Pragma("unroll 1")                                                \
        for (int kk = 0; kk < BK; kk += 2) {                               \
            const float* wk = W + (size_t)((k0b) + kk) * U + u0;           \
            float4 b0 = *(const float4*)(wk + 4 * ug);                     \
            float4 b1 = *(const float4*)(wk + 64 + 4 * ug);                \
            float4 b2 = *(const float4*)(wk + U + 4 * ug);                 \
            float4 b3 = *(const float4*)(wk + U + 64 + 4 * ug);            \
            _Pragma("unroll")                                              \
            for (int i = 0; i < 6; i++) {                                  \
                float2 a = *(const float2*)(ap + i * 256 + kk);            \
                acc[i][0] += a.x * b0.x;  acc[i][1] += a.x * b0.y;         \
                acc[i][2] += a.x * b0.z;  acc[i][3] += a.x * b0.w;         \
                acc[i][4] += a.x * b1.x;  acc[i][5] += a.x * b1.y;         \
                acc[i][6] += a.x * b1.z;  acc[i][7] += a.x * b1.w;         \
                acc[i][0] += a.y * b2.x;  acc[i][1] += a.y * b2.y;         \
                acc[i][2] += a.y * b2.z;  acc[i][3] += a.y * b2.w;         \
                acc[i][4] += a.y * b3.x;  acc[i][5] += a.y * b3.y;         \
                acc[i][6] += a.y * b3.z;  acc[i][7] += a.y * b3.w;         \
            }                                                              \
            if (w0) {  /* tail rows t=96..99, wave-uniform, all lanes */   \
                float2 a = *(const float2*)(ap + 6 * 256 + kk);            \
                acc[6][0] += a.x * b0.x;  acc[6][1] += a.x * b0.y;         \
                acc[6][2] += a.x * b0.z;  acc[6][3] += a.x * b0.w;         \
                acc[6][4] += a.x * b1.x;  acc[6][5] += a.x * b1.y;         \
                acc[6][6] += a.x * b1.z;  acc[6][7] += a.x * b1.w;         \
                acc[6][0] += a.y * b2.x;  acc[6][1] += a.y * b2.y;         \
                acc[6][2] += a.y * b2.z;  acc[6][3] += a.y * b2.w;         \
                acc[6][4] += a.y * b3.x;  acc[6][5] += a.y * b3.y;         \
                acc[6][6] += a.y * b3.z;  acc[6][7] += a.y * b3.w;         \
            }                                                              \
        }                                                                  \
    } while (0)

    // prologue: fill buffer 0
    STAGE(As0, 0);
    __syncthreads();   // auto vmcnt(0): As0 visible

    #pragma unroll 1
    for (int k0 = 0; k0 < F; k0 += 2 * BK) {
        STAGE(As1, k0 + BK);                  // async: next tile into As1
        COMPUTE(As0, k0);
        __syncthreads();                      // drains STAGE + readers done
        if (k0 + 2 * BK < F) STAGE(As0, k0 + 2 * BK);
        COMPUTE(As1, k0 + BK);
        __syncthreads();
    }

#undef STAGE
#undef COMPUTE

    // ---- bias ----
    float bb[8];
    {
        float4 bv0 = *(const float4*)(bias + u0 + 4 * ug);
        float4 bv1 = *(const float4*)(bias + u0 + 64 + 4 * ug);
        bb[0] = bv0.x; bb[1] = bv0.y; bb[2] = bv0.z; bb[3] = bv0.w;
        bb[4] = bv1.x; bb[5] = bv1.y; bb[6] = bv1.z; bb[7] = bv1.w;
    }

    // ---- chunked dump + LIF scan (2 x 50 t-rows) ----
    float v = 0.f, cnt = 0.f;
    float* sp = spikes + (size_t)b * T * U + u0 + tid;   // used when tid<UN

    #pragma unroll
    for (int c = 0; c < 2; c++) {
        #pragma unroll
        for (int i = 0; i < 7; i++) {
            const int t = i * 16 + tg;
            if (t >= c * CHUNK && t < c * CHUNK + CHUNK && t < TMAX) {
                const int r = t - c * CHUNK;
                float4 c0, c1;
                c0.x = acc[i][0] + bb[0]; c0.y = acc[i][1] + bb[1];
                c0.z = acc[i][2] + bb[2]; c0.w = acc[i][3] + bb[3];
                c1.x = acc[i][4] + bb[4]; c1.y = acc[i][5] + bb[5];
                c1.z = acc[i][6] + bb[6]; c1.w = acc[i][7] + bb[7];
                *(float4*)(smem + r * CS + 4 * ug)      = c0;
                *(float4*)(smem + r * CS + 64 + 4 * ug) = c1;
            }
        }
        __syncthreads();
        if (tid < UN) {
#pragma clang fp contract(off)
            // rounding matches numpy elementwise exactly:
            // v = 0.25*v + round(0.75*c); spike = v > 1.0; v -= spike.
            for (int r = 0; r < CHUNK; r++) {
                float cval = smem[r * CS + tid];
                v = 0.25f * v + 0.75f * cval;
                float s = (v > 1.0f) ? 1.0f : 0.0f;
                v -= s;
                cnt += s;
                sp[(size_t)(c * CHUNK + r) * U] = s;
            }
        }
        __syncthreads();   // scan done before chunk 1 overwrites Cs
    }
    if (tid < UN) counts[(size_t)b * U + u0 + tid] = cnt;
}

extern "C" void kernel_launch(void* const* d_in, const int* in_sizes, int n_in,
                              void* d_out, int out_size, void* d_ws, size_t ws_size,
                              hipStream_t stream) {
    const float* x    = (const float*)d_in[0];  // [B,T,F]
    const float* kern = (const float*)d_in[1];  // [F,U]
    const float* bias = (const float*)d_in[2];  // [U]
    float* out = (float*)d_out;

    const int U = in_sizes[2];                 // 1024
    const int F = in_sizes[1] / U;             // 1024
    const int R = in_sizes[0] / F;             // B*T = 25600
    const int B = out_size / U - R;            // 256
    const int T = R / B;                       // 100

    float* spikes = out;
    float* counts = out + (size_t)R * U;

    dim3 grid(U / UN, B);                      // (8, 256)
    fused_snn<<<grid, 256, 0, stream>>>(x, kern, bias, spikes, counts,
                                        B, T, F, U);
}

// Round 6
// 818.817 us; speedup vs baseline: 1.0389x; 1.0389x over previous
//
#include <hip/hip_runtime.h>

// Fused SpikingDenseLayer: B=256, T=100, F=K=1024, U=1024.
// One block = one (batch b, 128-wide u-tile), 256 threads.
// v7 = v6 + depth-1 register prefetch of W:
//  * v6 post-mortem: W direct-from-global removed the LDS bottleneck
//    (v5: 614 us LDS-pipe model, 630 measured) but the rolled loop made
//    the 4 W loads serial with ~200 cyc L2 latency per 2-k iteration ->
//    VALUBusy 56%, 790 us. Fix: software-pipeline W by ONE kk-iteration
//    (c0..c3 current, n0..n3 next; rotate at iter end). The waitcnt for
//    n lands one iteration (~224 FMA cyc) after issue -> latency covered.
//  * A stays in LDS via global_load_lds (linear [100][16], double-buffered
//    2 x 6.4 KB; bank-conflict counter 0 since v2). LDS demand ~42 cyc per
//    224 FMA cyc -> pipe no longer binding.
//  * kk loop stays rolled (#pragma unroll 1) -- v4 showed full unroll makes
//    hipcc hoist everything -> spill. No __launch_bounds__ min-waves arg
//    (measured hipcc cap ~= 256/arg would re-spill; allocator needs ~100).
//  * tail rows t=96..99 wave-uniform on wave 0; exactly 100 t-rows issued.
// Per-output FMA chain strictly k-ascending, same expression forms as the
// passing v5/v6 -> currents bitwise identical; scan math unchanged.

#define UN 128              // u-columns per block
#define BK 16               // k-slice staged per buffer
#define CS 132              // Cs row stride in floats (128 + 4)
#define CHUNK 50            // t-rows per scan chunk
#define TMAX 100

__device__ __forceinline__ void gload_lds16(const float* g, float* l) {
    __builtin_amdgcn_global_load_lds(
        (const __attribute__((address_space(1))) void*)g,
        (__attribute__((address_space(3))) void*)l,
        16, 0, 0);
}

__global__ __launch_bounds__(256) void fused_snn(
    const float* __restrict__ x,     // [B,T,F]
    const float* __restrict__ W,     // [F,U]
    const float* __restrict__ bias,  // [U]
    float* __restrict__ spikes,      // [B,T,U]
    float* __restrict__ counts,      // [B,U]
    int B, int T, int F, int U)
{
    // smem: As double-buffer (2 x 1600 floats) during GEMM; whole region
    // reused as Cs[50][132] for the scan.
    __shared__ __align__(16) float smem[CHUNK * CS];   // 6600 floats = 26.4 KB
    float* As0 = smem;           // [100][16] linear
    float* As1 = smem + 1600;    // [100][16] linear

    const int tid = threadIdx.x;
    const int tg  = tid >> 4;    // 0..15 -> t = i*16 + tg
    const int ug  = tid & 15;    // 0..15 -> u cols {4ug..} and {64+4ug..}
    const int u0  = blockIdx.x * UN;
    const int b   = blockIdx.y;

    float acc[7][8];
    #pragma unroll
    for (int i = 0; i < 7; i++)
        #pragma unroll
        for (int j = 0; j < 8; j++) acc[i][j] = 0.f;

    const float* xb = x + (size_t)b * T * F;

    // A staging: 100 rows x 64 B = 400 16-B slots; slot s = row s>>2,
    // byte (s&3)*16; LDS dest = slot*16 (linear, as global_load_lds needs).
    const float* ga0 = xb + (size_t)(tid >> 2) * F + (tid & 3) * 4;
    const float* ga1 = xb + (size_t)(64 + (tid >> 2)) * F + (tid & 3) * 4;
    const int la0 = tid * 4;
    const int la1 = (256 + tid) * 4;
    const bool a1on = (tid < 144);           // slots 256..399
    const bool w0   = (tid < 64);            // wave 0 owns tail rows 96..99

    // Per-lane W base: row k is wlane + k*U; u-halves at +0 and +64.
    const float* wlane = W + u0 + 4 * ug;

#define STAGE(buf, kof)                                   \
    do {                                                  \
        gload_lds16(ga0 + (kof), (buf) + la0);            \
        if (a1on) gload_lds16(ga1 + (kof), (buf) + la1);  \
    } while (0)

    // c0..c3 hold W rows (k, k+1) for the CURRENT kk; n0..n3 prefetch k+2.
#define COMPUTE(buf, k0b)                                                  \
    do {                                                                   \
        const float* ap = (buf) + tg * 16;                                 \
        _Pragma("unroll 1")                                                \
        for (int kk = 0; kk < BK; kk += 2) {                               \
            const int kn = ((k0b) + kk + 2 < F) ? ((k0b) + kk + 2) : 0;    \
            const float* wn = wlane + (size_t)kn * U;                      \
            float4 n0 = *(const float4*)(wn);                              \
            float4 n1 = *(const float4*)(wn + 64);                         \
            float4 n2 = *(const float4*)(wn + U);                          \
            float4 n3 = *(const float4*)(wn + U + 64);                     \
            _Pragma("unroll")                                              \
            for (int i = 0; i < 6; i++) {                                  \
                float2 a = *(const float2*)(ap + i * 256 + kk);            \
                acc[i][0] += a.x * c0.x;  acc[i][1] += a.x * c0.y;         \
                acc[i][2] += a.x * c0.z;  acc[i][3] += a.x * c0.w;         \
                acc[i][4] += a.x * c1.x;  acc[i][5] += a.x * c1.y;         \
                acc[i][6] += a.x * c1.z;  acc[i][7] += a.x * c1.w;         \
                acc[i][0] += a.y * c2.x;  acc[i][1] += a.y * c2.y;         \
                acc[i][2] += a.y * c2.z;  acc[i][3] += a.y * c2.w;         \
                acc[i][4] += a.y * c3.x;  acc[i][5] += a.y * c3.y;         \
                acc[i][6] += a.y * c3.z;  acc[i][7] += a.y * c3.w;         \
            }                                                              \
            if (w0) {  /* tail rows t=96..99, wave-uniform, all lanes */   \
                float2 a = *(const float2*)(ap + 6 * 256 + kk);            \
                acc[6][0] += a.x * c0.x;  acc[6][1] += a.x * c0.y;         \
                acc[6][2] += a.x * c0.z;  acc[6][3] += a.x * c0.w;         \
                acc[6][4] += a.x * c1.x;  acc[6][5] += a.x * c1.y;         \
                acc[6][6] += a.x * c1.z;  acc[6][7] += a.x * c1.w;         \
                acc[6][0] += a.y * c2.x;  acc[6][1] += a.y * c2.y;         \
                acc[6][2] += a.y * c2.z;  acc[6][3] += a.y * c2.w;         \
                acc[6][4] += a.y * c3.x;  acc[6][5] += a.y * c3.y;         \
                acc[6][6] += a.y * c3.z;  acc[6][7] += a.y * c3.w;         \
            }                                                              \
            c0 = n0; c1 = n1; c2 = n2; c3 = n3;                            \
        }                                                                  \
    } while (0)

    // prologue: fill buffer 0 and prefetch W rows k=0,1
    STAGE(As0, 0);
    float4 c0 = *(const float4*)(wlane);
    float4 c1 = *(const float4*)(wlane + 64);
    float4 c2 = *(const float4*)(wlane + U);
    float4 c3 = *(const float4*)(wlane + U + 64);
    __syncthreads();   // auto vmcnt(0): As0 visible

    #pragma unroll 1
    for (int k0 = 0; k0 < F; k0 += 2 * BK) {
        STAGE(As1, k0 + BK);                  // async: next tile into As1
        COMPUTE(As0, k0);
        __syncthreads();                      // drains STAGE + readers done
        if (k0 + 2 * BK < F) STAGE(As0, k0 + 2 * BK);
        COMPUTE(As1, k0 + BK);
        __syncthreads();
    }

#undef STAGE
#undef COMPUTE

    // ---- bias ----
    float bb[8];
    {
        float4 bv0 = *(const float4*)(bias + u0 + 4 * ug);
        float4 bv1 = *(const float4*)(bias + u0 + 64 + 4 * ug);
        bb[0] = bv0.x; bb[1] = bv0.y; bb[2] = bv0.z; bb[3] = bv0.w;
        bb[4] = bv1.x; bb[5] = bv1.y; bb[6] = bv1.z; bb[7] = bv1.w;
    }

    // ---- chunked dump + LIF scan (2 x 50 t-rows) ----
    float v = 0.f, cnt = 0.f;
    float* sp = spikes + (size_t)b * T * U + u0 + tid;   // used when tid<UN

    #pragma unroll
    for (int c = 0; c < 2; c++) {
        #pragma unroll
        for (int i = 0; i < 7; i++) {
            const int t = i * 16 + tg;
            if (t >= c * CHUNK && t < c * CHUNK + CHUNK && t < TMAX) {
                const int r = t - c * CHUNK;
                float4 d0, d1;
                d0.x = acc[i][0] + bb[0]; d0.y = acc[i][1] + bb[1];
                d0.z = acc[i][2] + bb[2]; d0.w = acc[i][3] + bb[3];
                d1.x = acc[i][4] + bb[4]; d1.y = acc[i][5] + bb[5];
                d1.z = acc[i][6] + bb[6]; d1.w = acc[i][7] + bb[7];
                *(float4*)(smem + r * CS + 4 * ug)      = d0;
                *(float4*)(smem + r * CS + 64 + 4 * ug) = d1;
            }
        }
        __syncthreads();
        if (tid < UN) {
#pragma clang fp contract(off)
            // rounding matches numpy elementwise exactly:
            // v = 0.25*v + round(0.75*c); spike = v > 1.0; v -= spike.
            for (int r = 0; r < CHUNK; r++) {
                float cval = smem[r * CS + tid];
                v = 0.25f * v + 0.75f * cval;
                float s = (v > 1.0f) ? 1.0f : 0.0f;
                v -= s;
                cnt += s;
                sp[(size_t)(c * CHUNK + r) * U] = s;
            }
        }
        __syncthreads();   // scan done before chunk 1 overwrites Cs
    }
    if (tid < UN) counts[(size_t)b * U + u0 + tid] = cnt;
}

extern "C" void kernel_launch(void* const* d_in, const int* in_sizes, int n_in,
                              void* d_out, int out_size, void* d_ws, size_t ws_size,
                              hipStream_t stream) {
    const float* x    = (const float*)d_in[0];  // [B,T,F]
    const float* kern = (const float*)d_in[1];  // [F,U]
    const float* bias = (const float*)d_in[2];  // [U]
    float* out = (float*)d_out;

    const int U = in_sizes[2];                 // 1024
    const int F = in_sizes[1] / U;             // 1024
    const int R = in_sizes[0] / F;             // B*T = 25600
    const int B = out_size / U - R;            // 256
    const int T = R / B;                       // 100

    float* spikes = out;
    float* counts = out + (size_t)R * U;

    dim3 grid(U / UN, B);                      // (8, 256)
    fused_snn<<<grid, 256, 0, stream>>>(x, kern, bias, spikes, counts,
                                        B, T, F, U);
}